// Round 1
// 416.935 us; speedup vs baseline: 1.0036x; 1.0036x over previous
//
#include <hip/hip_runtime.h>

#define ROWS 131072
#define COLS 256
#define NM   128   // num masked = COLS/2

// One wave (64 lanes) per row; 4 rows per 256-thread block.
// v2: rank-compact mo/ui/ud into per-wave LDS staging, then write every
// output row segment as a full-width coalesced float2 per lane
// (store instrs per row: 13 scattered dwords -> 4 coalesced dwordx2).
__global__ __launch_bounds__(256) void masker_kernel(
    const float* __restrict__ x,
    const int*   __restrict__ sidx,
    float*       __restrict__ out)
{
    __shared__ unsigned char flags[4][256];
    __shared__ float s_mo[4][NM];   // masked_indices staging (per wave)
    __shared__ float s_ui[4][NM];   // unmasked_indices staging
    __shared__ float s_ud[4][NM];   // unmasked_data staging

    const int wave = threadIdx.x >> 6;
    const int lane = threadIdx.x & 63;
    const long long row = (long long)blockIdx.x * 4 + wave;

    // zero this row's flag array: 64 lanes x 4 bytes = 256 bytes
    ((unsigned int*)flags[wave])[lane] = 0u;
    __syncthreads();

    // scatter first half of the permutation (the masked set): 128 ints, 2/lane
    const int2 mi = ((const int2*)(sidx + row * COLS))[lane];
    flags[wave][mi.x] = 1;
    flags[wave][mi.y] = 1;
    __syncthreads();

    // build 256-bit membership mask via 4 ballots; also load x coalesced
    unsigned long long b[4];
    int   f[4];
    float xv[4];
    const float* xrow = x + row * COLS;
#pragma unroll
    for (int k = 0; k < 4; ++k) {
        const int c = 64 * k + lane;
        f[k]  = flags[wave][c];
        xv[k] = xrow[c];
        b[k]  = __ballot(f[k] != 0);
    }

    const unsigned long long lt = (1ull << lane) - 1ull;

    // rank-compact into LDS staging (writes are conflict-free: consecutive
    // set/unset lanes produce consecutive dword addresses)
    int pre = 0;  // masked count in columns [0, 64*k)
#pragma unroll
    for (int k = 0; k < 4; ++k) {
        const int c  = 64 * k + lane;
        const int mb = pre + __popcll(b[k] & lt);  // masked cols < c
        if (f[k]) {
            s_mo[wave][mb] = (float)c;
        } else {
            const int u = c - mb;                  // unmasked cols < c
            s_ui[wave][u] = (float)c;
            s_ud[wave][u] = xv[k];
        }
        pre += __popcll(b[k]);
    }

    // Same-wave LDS RAW: compiler inserts s_waitcnt lgkmcnt before reads;
    // no cross-wave sharing of the staging arrays, so no barrier needed.
    float* md = out;                          // masked_data   (zeros)
    float* mo = out + (long long)ROWS * NM;   // masked_indices
    float* ud = out + 2ll * ROWS * NM;        // unmasked_data
    float* ui = out + 3ll * ROWS * NM;        // unmasked_indices
    const long long obase = row * NM;

    // 4 fully-coalesced 512B row-segment writes (dwordx2 per lane)
    ((float2*)(md + obase))[lane] = make_float2(0.0f, 0.0f);
    ((float2*)(mo + obase))[lane] = ((const float2*)s_mo[wave])[lane];
    ((float2*)(ud + obase))[lane] = ((const float2*)s_ud[wave])[lane];
    ((float2*)(ui + obase))[lane] = ((const float2*)s_ui[wave])[lane];
}

extern "C" void kernel_launch(void* const* d_in, const int* in_sizes, int n_in,
                              void* d_out, int out_size, void* d_ws, size_t ws_size,
                              hipStream_t stream) {
    const float* x    = (const float*)d_in[0];
    const int*   sidx = (const int*)d_in[1];
    float*       out  = (float*)d_out;
    masker_kernel<<<ROWS / 4, 256, 0, stream>>>(x, sidx, out);
}